// Round 3
// baseline (122.682 us; speedup 1.0000x reference)
//
#include <hip/hip_runtime.h>

#define N_PTS 16384
#define M_CENT 2048
#define MAXS 64
#define WPB 4   // waves (centroids) per block

__global__ __launch_bounds__(256) void ball_query_kernel(
    const float* __restrict__ pcs,      // [B, N, 3]
    const float* __restrict__ cent,     // [B, M, 3]
    int* __restrict__ out)              // [B, M, 64] int32 indices (harness reads int32)
{
#pragma clang fp contract(off)
    __shared__ int slots[WPB][MAXS];

    const int lane = threadIdx.x & 63;
    const int wid  = threadIdx.x >> 6;
    const int cg   = blockIdx.x * WPB + wid;   // global centroid id in [0, B*M)
    const int b    = cg >> 11;                 // / M_CENT (2048)

    // centroid coords + |c|^2 with reference op order: (cx^2+cy^2)+cz^2
    const float* cp = cent + (size_t)cg * 3;
    const float cx = cp[0], cy = cp[1], cz = cp[2];
    float c2 = cx * cx;
    c2 += cy * cy;
    c2 += cz * cz;
    const float r2 = 0.04f;

    const float* pbase = pcs + (size_t)b * N_PTS * 3;

    int count = 0;  // wave-uniform running hit count
    for (int base = 0; base < N_PTS; base += 64) {
        const int i = base + lane;
        const float* pp = pbase + (size_t)i * 3;
        const float px = pp[0], py = pp[1], pz = pp[2];

        // |p|^2 and c.p, sequential order to match numpy ref; no fma (contract off)
        float p2 = px * px;
        p2 += py * py;
        p2 += pz * pz;
        float cr = cx * px;
        cr += cy * py;
        cr += cz * pz;
        const float d2 = (c2 + p2) - 2.0f * cr;

        const bool hit = d2 <= r2;
        const unsigned long long mask = __ballot(hit);
        if (hit) {
            const int pos = count + __popcll(mask & ((1ull << lane) - 1ull));
            if (pos < MAXS) slots[wid][pos] = i;
        }
        count += (int)__popcll(mask);
        if (count >= MAXS) break;   // first 64 in ascending order found
    }

    __syncthreads();  // every thread reaches this exactly once

    const int cnt = count < MAXS ? count : MAXS;
    int val;
    if (cnt == 0) {
        val = N_PTS;  // reference pads all-N when no hits (idx==N -> first==N)
    } else {
        val = (lane < cnt) ? slots[wid][lane] : slots[wid][0];
    }
    out[((size_t)cg << 6) + lane] = val;
}

extern "C" void kernel_launch(void* const* d_in, const int* in_sizes, int n_in,
                              void* d_out, int out_size, void* d_ws, size_t ws_size,
                              hipStream_t stream) {
    const float* pcs  = (const float*)d_in[0];
    const float* cent = (const float*)d_in[1];
    int* out = (int*)d_out;

    const int B = in_sizes[0] / (N_PTS * 3);     // 4
    const int total_centroids = B * M_CENT;      // 8192
    const int grid = total_centroids / WPB;      // 2048 blocks x 256 threads

    ball_query_kernel<<<grid, 256, 0, stream>>>(pcs, cent, out);
}

// Round 4
// 86.213 us; speedup vs baseline: 1.4230x; 1.4230x over previous
//
#include <hip/hip_runtime.h>

#define N_PTS 16384
#define M_CENT 2048
#define MAXS 64
#define WPB 4    // waves (centroids) per block
#define CHUNK 256  // points per wave-iteration (4 per lane)

__global__ __launch_bounds__(256) void ball_query_kernel(
    const float* __restrict__ pcs,      // [B, N, 3]
    const float* __restrict__ cent,     // [B, M, 3]
    int* __restrict__ out)              // [B, M, 64] int32 indices
{
#pragma clang fp contract(off)
    __shared__ int slots[WPB][MAXS];

    const int lane = threadIdx.x & 63;
    const int wid  = threadIdx.x >> 6;
    const int cg   = blockIdx.x * WPB + wid;   // global centroid id in [0, B*M)
    const int b    = cg >> 11;                 // / M_CENT (2048)

    const float* cp = cent + (size_t)cg * 3;
    const float cx = cp[0], cy = cp[1], cz = cp[2];
    float c2 = cx * cx;
    c2 += cy * cy;
    c2 += cz * cz;
    const float r2 = 0.04f;

    const float* pbase = pcs + (size_t)b * N_PTS * 3;

    // Each lane handles points [base + 4*lane, base + 4*lane + 3]:
    // 12 consecutive floats = 3 aligned float4 loads (48B/lane, coalesced).
    const float4* q = (const float4*)(pbase) + (size_t)lane * 3;  // advance by 16 float4/chunk

    int count = 0;                 // wave-uniform running hit count
    int base = 0;
    float4 a = q[0], bb = q[1], cc = q[2];   // chunk 0

    while (true) {
        // ---- prefetch next chunk (wave-uniform condition) ----
        const int nbase = base + CHUNK;
        const bool have_next = nbase < N_PTS;
        float4 na, nb, nc;
        if (have_next) {
            const float4* qn = q + (size_t)(nbase >> 4) * 16 - ((size_t)(base >> 4) * 16);
            // simpler: recompute from scratch
            const float4* qq = (const float4*)(pbase) + (size_t)(nbase / 4) * 3 + (size_t)lane * 3;
            na = qq[0]; nb = qq[1]; nc = qq[2];
            (void)qn;
        }

        // ---- process current chunk: 4 points per lane ----
        // P0=(a.x,a.y,a.z) P1=(a.w,bb.x,bb.y) P2=(bb.z,bb.w,cc.x) P3=(cc.y,cc.z,cc.w)
        float p2, cr, d2;
        p2 = a.x * a.x;  p2 += a.y * a.y;  p2 += a.z * a.z;
        cr = cx * a.x;   cr += cy * a.y;   cr += cz * a.z;
        d2 = (c2 + p2) - 2.0f * cr;
        const bool h0 = d2 <= r2;

        p2 = a.w * a.w;  p2 += bb.x * bb.x;  p2 += bb.y * bb.y;
        cr = cx * a.w;   cr += cy * bb.x;    cr += cz * bb.y;
        d2 = (c2 + p2) - 2.0f * cr;
        const bool h1 = d2 <= r2;

        p2 = bb.z * bb.z;  p2 += bb.w * bb.w;  p2 += cc.x * cc.x;
        cr = cx * bb.z;    cr += cy * bb.w;    cr += cz * cc.x;
        d2 = (c2 + p2) - 2.0f * cr;
        const bool h2 = d2 <= r2;

        p2 = cc.y * cc.y;  p2 += cc.z * cc.z;  p2 += cc.w * cc.w;
        cr = cx * cc.y;    cr += cy * cc.z;    cr += cz * cc.w;
        d2 = (c2 + p2) - 2.0f * cr;
        const bool h3 = d2 <= r2;

        const unsigned long long m0 = __ballot(h0);
        const unsigned long long m1 = __ballot(h1);
        const unsigned long long m2 = __ballot(h2);
        const unsigned long long m3 = __ballot(h3);
        const unsigned long long pre = (1ull << lane) - 1ull;

        // rank of this lane's point j = count + hits at lanes<lane (any j)
        //                             + hits at this lane with j'<j
        const int below = (int)__popcll(m0 & pre) + (int)__popcll(m1 & pre)
                        + (int)__popcll(m2 & pre) + (int)__popcll(m3 & pre);
        const int r0 = count + below;
        const int r1 = r0 + (int)((m0 >> lane) & 1ull);
        const int r2i = r1 + (int)((m1 >> lane) & 1ull);
        const int r3 = r2i + (int)((m2 >> lane) & 1ull);

        const int pidx = base + 4 * lane;
        if (h0 && r0  < MAXS) slots[wid][r0]  = pidx;
        if (h1 && r1  < MAXS) slots[wid][r1]  = pidx + 1;
        if (h2 && r2i < MAXS) slots[wid][r2i] = pidx + 2;
        if (h3 && r3  < MAXS) slots[wid][r3]  = pidx + 3;

        count += (int)__popcll(m0) + (int)__popcll(m1)
               + (int)__popcll(m2) + (int)__popcll(m3);

        if (count >= MAXS || !have_next) break;
        a = na; bb = nb; cc = nc; base = nbase;
    }

    __syncthreads();  // every thread reaches this exactly once

    const int cnt = count < MAXS ? count : MAXS;
    int val;
    if (cnt == 0) {
        val = N_PTS;  // no hits: reference pads with N
    } else {
        val = (lane < cnt) ? slots[wid][lane] : slots[wid][0];
    }
    out[((size_t)cg << 6) + lane] = val;
}

extern "C" void kernel_launch(void* const* d_in, const int* in_sizes, int n_in,
                              void* d_out, int out_size, void* d_ws, size_t ws_size,
                              hipStream_t stream) {
    const float* pcs  = (const float*)d_in[0];
    const float* cent = (const float*)d_in[1];
    int* out = (int*)d_out;

    const int B = in_sizes[0] / (N_PTS * 3);     // 4
    const int total_centroids = B * M_CENT;      // 8192
    const int grid = total_centroids / WPB;      // 2048 blocks x 256 threads

    ball_query_kernel<<<grid, 256, 0, stream>>>(pcs, cent, out);
}

// Round 6
// 76.841 us; speedup vs baseline: 1.5966x; 1.1220x over previous
//
#include <hip/hip_runtime.h>

#define N_PTS 16384
#define M_CENT 2048
#define MAXS 64
#define NWAVE 4
#define NITER 16   // 16 x 1024 points = 16384

// One block = one centroid. 4 waves x 64 lanes x 4 points = 1024 points/iter.
__global__ __launch_bounds__(256) void ball_query_kernel(
    const float* __restrict__ pcs,      // [B, N, 3]
    const float* __restrict__ cent,     // [B, M, 3]
    int* __restrict__ out)              // [B, M, 64] int32 indices
{
#pragma clang fp contract(off)
    __shared__ int slots[MAXS];
    __shared__ int wavecnt[2][NWAVE];   // parity double-buffer: 1 barrier/iter

    const int lane = threadIdx.x & 63;
    const int wid  = threadIdx.x >> 6;
    const int cg   = blockIdx.x;        // centroid id in [0, B*M)
    const int b    = cg >> 11;          // / M_CENT

    const float* cp = cent + (size_t)cg * 3;
    const float cx = cp[0], cy = cp[1], cz = cp[2];
    float c2 = cx * cx;
    c2 += cy * cy;
    c2 += cz * cz;
    const float r2 = 0.04f;

    const float* pbase = pcs + (size_t)b * N_PTS * 3;
    const float4* pq = (const float4*)pbase;
    // thread handles points 4*(iter*256 + toff) .. +3  => float4 index 3*(iter*256+toff)
    const int toff = wid * 64 + lane;

    int count = 0;                      // block-uniform running hit count
    size_t qi = (size_t)3 * toff;
    float4 a = pq[qi], bb = pq[qi + 1], cc = pq[qi + 2];

    int iter = 0;
    while (true) {
        // ---- prefetch next chunk (block-uniform condition) ----
        const bool have_next = (iter + 1) < NITER;
        float4 na, nb, nc;
        if (have_next) {
            const size_t nq = (size_t)3 * ((iter + 1) * 256 + toff);
            na = pq[nq]; nb = pq[nq + 1]; nc = pq[nq + 2];
        }

        // ---- distance tests: 4 points per lane ----
        // P0=(a.x,a.y,a.z) P1=(a.w,bb.x,bb.y) P2=(bb.z,bb.w,cc.x) P3=(cc.y,cc.z,cc.w)
        float p2, cr, d2;
        p2 = a.x * a.x;  p2 += a.y * a.y;  p2 += a.z * a.z;
        cr = cx * a.x;   cr += cy * a.y;   cr += cz * a.z;
        d2 = (c2 + p2) - 2.0f * cr;
        const bool h0 = d2 <= r2;

        p2 = a.w * a.w;  p2 += bb.x * bb.x;  p2 += bb.y * bb.y;
        cr = cx * a.w;   cr += cy * bb.x;    cr += cz * bb.y;
        d2 = (c2 + p2) - 2.0f * cr;
        const bool h1 = d2 <= r2;

        p2 = bb.z * bb.z;  p2 += bb.w * bb.w;  p2 += cc.x * cc.x;
        cr = cx * bb.z;    cr += cy * bb.w;    cr += cz * cc.x;
        d2 = (c2 + p2) - 2.0f * cr;
        const bool h2 = d2 <= r2;

        p2 = cc.y * cc.y;  p2 += cc.z * cc.z;  p2 += cc.w * cc.w;
        cr = cx * cc.y;    cr += cy * cc.z;    cr += cz * cc.w;
        d2 = (c2 + p2) - 2.0f * cr;
        const bool h3 = d2 <= r2;

        const unsigned long long m0 = __ballot(h0);
        const unsigned long long m1 = __ballot(h1);
        const unsigned long long m2 = __ballot(h2);
        const unsigned long long m3 = __ballot(h3);
        const unsigned long long pre = (1ull << lane) - 1ull;

        const int mycnt = (int)__popcll(m0) + (int)__popcll(m1)
                        + (int)__popcll(m2) + (int)__popcll(m3);
        if (lane == 0) wavecnt[iter & 1][wid] = mycnt;
        __syncthreads();

        // cross-wave exclusive prefix + block total (LDS broadcast reads)
        int prew = 0, tot = 0;
#pragma unroll
        for (int w = 0; w < NWAVE; ++w) {
            const int c = wavecnt[iter & 1][w];
            tot += c;
            if (w < wid) prew += c;
        }

        // within-wave ranks
        const int below = (int)__popcll(m0 & pre) + (int)__popcll(m1 & pre)
                        + (int)__popcll(m2 & pre) + (int)__popcll(m3 & pre);
        const int r0 = count + prew + below;
        const int r1 = r0  + (int)((m0 >> lane) & 1ull);
        const int r2i = r1 + (int)((m1 >> lane) & 1ull);
        const int r3 = r2i + (int)((m2 >> lane) & 1ull);

        const int pidx = 4 * (iter * 256 + toff);
        if (h0 && r0  < MAXS) slots[r0]  = pidx;
        if (h1 && r1  < MAXS) slots[r1]  = pidx + 1;
        if (h2 && r2i < MAXS) slots[r2i] = pidx + 2;
        if (h3 && r3  < MAXS) slots[r3]  = pidx + 3;

        count += tot;                    // block-uniform
        ++iter;
        if (count >= MAXS || iter >= NITER) break;   // uniform exit: barriers stay matched
        a = na; bb = nb; cc = nc;
    }

    __syncthreads();                     // slots visible; reached uniformly

    if (wid == 0) {
        const int cnt = count < MAXS ? count : MAXS;
        int val;
        if (cnt == 0) {
            val = N_PTS;                 // no hits: reference pads with N
        } else {
            val = (lane < cnt) ? slots[lane] : slots[0];
        }
        out[((size_t)cg << 6) + lane] = val;
    }
}

extern "C" void kernel_launch(void* const* d_in, const int* in_sizes, int n_in,
                              void* d_out, int out_size, void* d_ws, size_t ws_size,
                              hipStream_t stream) {
    const float* pcs  = (const float*)d_in[0];
    const float* cent = (const float*)d_in[1];
    int* out = (int*)d_out;

    const int B = in_sizes[0] / (N_PTS * 3);     // 4
    const int grid = B * M_CENT;                 // 8192 blocks, 1 centroid each

    ball_query_kernel<<<grid, 256, 0, stream>>>(pcs, cent, out);
}